// Round 1
// baseline (420.899 us; speedup 1.0000x reference)
//
#include <hip/hip_runtime.h>
#include <math.h>

#define BB 8
#define NPTS 80000
#define KK 5
#define FF 20
#define GG 64            // blocks per batch
#define TILE 64
#define NTILES (NPTS / TILE)   // 1250, exact

// workspace layout (float offsets)
#define WS_CM 0          // cur means  [B,K,F] = 800
#define WS_CV 800        // cur var    = 800
#define WS_CP 1600       // cur pi     = 40
#define WS_A  1640       // A coef     = 40
#define WS_D  1680       // d coef     = 800
#define WS_E  2480       // e coef     = 800
#define WS_S0 3280       // 40
#define WS_S1 3320       // 800
#define WS_S2 4120       // 800

// ---- compute A/d/e from (means,var,pi) and zero accumulators ----
__device__ __forceinline__ void make_coefs(const float* __restrict__ means,
                                           const float* __restrict__ var,
                                           const float* __restrict__ pi,
                                           float* __restrict__ A, float* __restrict__ D,
                                           float* __restrict__ E, int t) {
    if (t < BB * KK) {
        float sumlog = 0.f, summ2 = 0.f;
        for (int f = 0; f < FF; ++f) {
            float v = var[t * FF + f];
            float m = means[t * FF + f];
            float ic = 1.f / (v + 1e-6f);
            sumlog += logf(6.283185307179586f * v);
            summ2  += ic * m * m;
            D[t * FF + f] = ic * m;
            E[t * FF + f] = -0.5f * ic;
        }
        A[t] = logf(pi[t]) - 0.5f * sumlog - 0.5f * summ2;
    }
}

__global__ void prepare_kernel(const float* __restrict__ means, const float* __restrict__ var,
                               const float* __restrict__ pi, float* __restrict__ ws) {
    int t = threadIdx.x;
    float* S0 = ws + WS_S0; float* S1 = ws + WS_S1; float* S2 = ws + WS_S2;
    for (int i = t; i < BB * KK; i += blockDim.x) S0[i] = 0.f;
    for (int i = t; i < BB * KK * FF; i += blockDim.x) { S1[i] = 0.f; S2[i] = 0.f; }
    make_coefs(means, var, pi, ws + WS_A, ws + WS_D, ws + WS_E, t);
}

// ---- E-step: per-wave cluster, per-lane point; accumulate or write outputs ----
template <bool WRITE_OUT>
__global__ __launch_bounds__(320) void estep_kernel(const float* __restrict__ data,
                                                    const float* __restrict__ ws_ro,
                                                    float* __restrict__ ws_rw,
                                                    float* __restrict__ out_ll,
                                                    float* __restrict__ out_post) {
    __shared__ float xs[TILE][FF + 1];   // +1 pad: stride 21 -> <=2-way bank alias (free)
    __shared__ float lls[KK][TILE];

    const int b    = blockIdx.x / GG;
    const int g    = blockIdx.x % GG;
    const int tid  = threadIdx.x;
    const int w    = __builtin_amdgcn_readfirstlane(tid >> 6);   // cluster k, wave-uniform
    const int lane = tid & 63;
    const int sp   = (tid * 4) / FF;     // staging LDS row
    const int sf   = (tid * 4) % FF;     // staging LDS col (always multiple of 4)

    const float* A = ws_ro + WS_A;
    const float* D = ws_ro + WS_D;
    const float* E = ws_ro + WS_E;

    const float Ak = A[b * KK + w];
    float dk[FF], ek[FF];
#pragma unroll
    for (int f = 0; f < FF; ++f) {
        dk[f] = D[(b * KK + w) * FF + f];
        ek[f] = E[(b * KK + w) * FF + f];
    }

    float s0 = 0.f, s1[FF], s2[FF];
    if (!WRITE_OUT) {
#pragma unroll
        for (int f = 0; f < FF; ++f) { s1[f] = 0.f; s2[f] = 0.f; }
    }

    const float* dbase = data + (size_t)b * NPTS * FF;

    for (int t = g; t < NTILES; t += GG) {
        // stage 64 points (5120 B) fully coalesced: one float4 per thread
        float4 v = ((const float4*)(dbase + (size_t)t * TILE * FF))[tid];
        xs[sp][sf] = v.x; xs[sp][sf + 1] = v.y; xs[sp][sf + 2] = v.z; xs[sp][sf + 3] = v.w;
        __syncthreads();

        float x[FF];
        float z = Ak;
#pragma unroll
        for (int f = 0; f < FF; ++f) {
            x[f] = xs[lane][f];
            z += x[f] * fmaf(ek[f], x[f], dk[f]);
        }
        lls[w][lane] = z;
        __syncthreads();

        float l0 = lls[0][lane], l1 = lls[1][lane], l2 = lls[2][lane],
              l3 = lls[3][lane], l4 = lls[4][lane];
        float mx = fmaxf(fmaxf(fmaxf(l0, l1), fmaxf(l2, l3)), l4);
        float e0 = __expf(l0 - mx), e1 = __expf(l1 - mx), e2 = __expf(l2 - mx),
              e3 = __expf(l3 - mx), e4 = __expf(l4 - mx);
        float inv = 1.f / (e0 + e1 + e2 + e3 + e4);
        float ew  = (w == 0) ? e0 : (w == 1) ? e1 : (w == 2) ? e2 : (w == 3) ? e3 : e4;
        float post = ew * inv;

        if (WRITE_OUT) {
            size_t o = ((size_t)b * NPTS + (size_t)t * TILE + lane) * KK + w;
            out_ll[o]   = z;
            out_post[o] = post;
        } else {
            s0 += post;
#pragma unroll
            for (int f = 0; f < FF; ++f) {
                float px = post * x[f];
                s1[f] += px;
                s2[f] += px * x[f];
            }
        }
        // next iteration's staging write to xs is safe: xs reads ended before the
        // 2nd sync; lls reads here end before next iteration's 1st sync.
    }

    if (!WRITE_OUT) {
        float* S0 = ws_rw + WS_S0; float* S1 = ws_rw + WS_S1; float* S2 = ws_rw + WS_S2;
#pragma unroll
        for (int off = 32; off > 0; off >>= 1) {
            s0 += __shfl_down(s0, off);
#pragma unroll
            for (int f = 0; f < FF; ++f) {
                s1[f] += __shfl_down(s1[f], off);
                s2[f] += __shfl_down(s2[f], off);
            }
        }
        if (lane == 0) {
            atomicAdd(&S0[b * KK + w], s0);
#pragma unroll
            for (int f = 0; f < FF; ++f) {
                atomicAdd(&S1[(b * KK + w) * FF + f], s1[f]);
                atomicAdd(&S2[(b * KK + w) * FF + f], s2[f]);
            }
        }
    }
}

// ---- M-step + coefs for next iteration + zero accumulators (fused) ----
__global__ void update_kernel(float* __restrict__ ws,
                              float* __restrict__ om, float* __restrict__ ov,
                              float* __restrict__ op, int write_out) {
    int t = threadIdx.x;
    const float* S0 = ws + WS_S0; const float* S1 = ws + WS_S1; const float* S2 = ws + WS_S2;
    float* cm = ws + WS_CM; float* cv = ws + WS_CV; float* cp = ws + WS_CP;

    for (int i = t; i < BB * KK * FF; i += blockDim.x) {
        int bk = i / FF;
        float sz  = S0[bk];
        float den = sz + 1e-7f;
        float m   = S1[i] / den;
        float var = (S2[i] - 2.f * m * S1[i] + m * m * sz) / den + 1e-6f;
        cm[i] = m; cv[i] = var;
        if (write_out) { om[i] = m; ov[i] = var; }
    }
    if (t < BB * KK) {
        int b = t / KK;
        float tot = 0.f;
        for (int j = 0; j < KK; ++j) tot += S0[b * KK + j];
        float pr = (S0[t] / (float)NPTS) / fmaxf(tot / (float)NPTS, 1e-12f);
        cp[t] = pr;
        if (write_out) op[t] = pr;
    }
    __syncthreads();
    // coefficients for the next E-step from the just-updated params
    make_coefs(cm, cv, cp, ws + WS_A, ws + WS_D, ws + WS_E, t);
    // re-zero accumulators for the next E-step
    float* zS0 = ws + WS_S0; float* zS1 = ws + WS_S1; float* zS2 = ws + WS_S2;
    for (int i = t; i < BB * KK; i += blockDim.x) zS0[i] = 0.f;
    for (int i = t; i < BB * KK * FF; i += blockDim.x) { zS1[i] = 0.f; zS2[i] = 0.f; }
}

extern "C" void kernel_launch(void* const* d_in, const int* in_sizes, int n_in,
                              void* d_out, int out_size, void* d_ws, size_t ws_size,
                              hipStream_t stream) {
    const float* data     = (const float*)d_in[0];
    const float* in_means = (const float*)d_in[1];
    const float* in_var   = (const float*)d_in[2];
    const float* in_pi    = (const float*)d_in[3];
    float* ws  = (float*)d_ws;
    float* out = (float*)d_out;

    float* out_ll   = out;
    float* out_post = out + (size_t)BB * NPTS * KK;
    float* om       = out + 2 * (size_t)BB * NPTS * KK;
    float* ov       = om + BB * KK * FF;
    float* op       = ov + BB * KK * FF;

    // iteration 0 coefs from inputs + zero accumulators
    prepare_kernel<<<1, 256, 0, stream>>>(in_means, in_var, in_pi, ws);

    for (int it = 0; it < 5; ++it) {
        estep_kernel<false><<<BB * GG, 320, 0, stream>>>(data, ws, ws, nullptr, nullptr);
        update_kernel<<<1, 256, 0, stream>>>(ws, om, ov, op, (it == 4) ? 1 : 0);
    }
    // final E-step with post-loop params: write ll/post outputs
    estep_kernel<true><<<BB * GG, 320, 0, stream>>>(data, ws, ws, out_ll, out_post);
}